// Round 6
// baseline (165.539 us; speedup 1.0000x reference)
//
#include <hip/hip_runtime.h>
#include <hip/hip_bf16.h>
#include <math.h>
#include <stdint.h>

using bf16 = __hip_bfloat16;
typedef __attribute__((ext_vector_type(8))) short short8;
typedef __attribute__((ext_vector_type(4))) short short4v;
typedef __attribute__((ext_vector_type(4))) float float4v;

#define MFMA16(a, b, c) __builtin_amdgcn_mfma_f32_16x16x32_bf16(a, b, c, 0, 0, 0)

__device__ __forceinline__ short bfbits(float f) {
  bf16 h = (bf16)f;
  return *(short*)&h;
}

__device__ __forceinline__ short8 ld_cvt8(const float* p) {
  union { float4v v[2]; float f[8]; } u;
  u.v[0] = *(const float4v*)p;
  u.v[1] = *(const float4v*)(p + 4);
  short8 r;
#pragma unroll
  for (int j = 0; j < 8; j++) r[j] = bfbits(u.f[j]);
  return r;
}

// global -> LDS direct copy, 16B per lane. LDS dest = uniform base + lane*16.
__device__ __forceinline__ void gload16(const bf16* g, bf16* l) {
  __builtin_amdgcn_global_load_lds(
      (const __attribute__((address_space(1))) void*)g,
      (__attribute__((address_space(3))) void*)l, 16, 0, 0);
}

// ---------------------------------------------------------------------------
// One-shot fp32 -> bf16 conversion of x and the 4 weights.
// Concatenated elem space: [x:4194304][Wq,Wk,Wv,Wout: 262144 each].
// ---------------------------------------------------------------------------
__global__ __launch_bounds__(256) void conv_all(
    const float* __restrict__ x, const float* __restrict__ w0,
    const float* __restrict__ w1, const float* __restrict__ w2,
    const float* __restrict__ w3, bf16* __restrict__ cx,
    bf16* __restrict__ cw) {
  size_t gid = ((size_t)blockIdx.x * 256 + threadIdx.x) * 8;
  const float* src;
  bf16* dst;
  size_t off;
  if (gid < 4194304) {
    src = x; dst = cx; off = gid;
  } else {
    size_t r = gid - 4194304;
    int wi = (int)(r >> 18);
    src = wi == 0 ? w0 : wi == 1 ? w1 : wi == 2 ? w2 : w3;
    dst = cw + ((size_t)wi << 18);
    off = r & 262143;
  }
  *(short8*)(dst + off) = ld_cvt8(src + off);
}

// ---------------------------------------------------------------------------
// GEMM (NT, all-bf16): C[MTx128] tile of A[M,512] * W[N,512]^T.
// m97-structure staging: global_load_lds width=16 into linear [rows][64] LDS,
// XOR-swizzled on BOTH sides (pre-swizzled global source column + swizzled
// ds_read_b128), BK=64 (2 MFMA sub-steps per barrier pair, 8 k-steps).
// MODE 0: out[b,h,t,d] bf16 scaled (Q,K). MODE 1: out[m,n] fp32 (proj).
// MODE 2: out[b,h,d,t] bf16 (V^T).
// ---------------------------------------------------------------------------
template <int MODE, int MT>
__device__ __forceinline__ void gemm_body(bf16* As, bf16* Bs,
                                          const bf16* __restrict__ A,
                                          const bf16* __restrict__ W,
                                          void* __restrict__ outp,
                                          float oscale) {
  constexpr int MI = MT / 32;
  const int bm = blockIdx.x * MT, bn = blockIdx.y * 128;
  const int tid = threadIdx.x;
  const int lane = tid & 63;
  const int wave = tid >> 6;
  const int lr = lane & 15, quad = lane >> 4;
  const int wm = (wave & 1) * (MT / 2), wn = (wave >> 1) * 64;

  const int srow = lane >> 3;
  const int scl = (lane & 7) ^ (srow & 7);
  const int rsw = lr & 7;

  float4v acc[MI][4] = {};

  for (int k0 = 0; k0 < 512; k0 += 64) {
    __syncthreads();  // previous sub-step's LDS reads complete
#pragma unroll
    for (int j = 0; j < MT / 32; j++) {  // A: MT/8 instrs, MT/32 per wave
      const int m = wave + 4 * j;        // 8-row group index
      gload16(&A[(size_t)(bm + 8 * m + srow) * 512 + k0 + scl * 8],
              &As[(8 * m) * 64]);
    }
#pragma unroll
    for (int j = 0; j < 4; j++) {        // B: 16 instrs, 4 per wave
      const int m = wave + 4 * j;
      gload16(&W[(size_t)(bn + 8 * m + srow) * 512 + k0 + scl * 8],
              &Bs[(8 * m) * 64]);
    }
    __syncthreads();  // barrier drains vmcnt: staged tile visible
#pragma unroll
    for (int kk = 0; kk < 2; kk++) {
      short8 af[MI], bfv[4];
#pragma unroll
      for (int i = 0; i < MI; i++)
        af[i] = *(const short8*)
            &As[(wm + i * 16 + lr) * 64 + ((4 * kk + quad) ^ rsw) * 8];
#pragma unroll
      for (int i = 0; i < 4; i++)
        bfv[i] = *(const short8*)
            &Bs[(wn + i * 16 + lr) * 64 + ((4 * kk + quad) ^ rsw) * 8];
#pragma unroll
      for (int mi = 0; mi < MI; mi++)
#pragma unroll
        for (int ni = 0; ni < 4; ni++)
          acc[mi][ni] = MFMA16(af[mi], bfv[ni], acc[mi][ni]);
    }
  }

  const int row0 = bm + wm + quad * 4;
  const int col0 = bn + wn + lr;
#pragma unroll
  for (int mi = 0; mi < MI; mi++) {
#pragma unroll
    for (int ni = 0; ni < 4; ni++) {
      const int col = col0 + ni * 16;
      if (MODE == 1) {
        float* out = (float*)outp;
#pragma unroll
        for (int i = 0; i < 4; i++) {
          int m = row0 + mi * 16 + i;
          out[(size_t)m * 512 + col] = acc[mi][ni][i];
        }
      } else if (MODE == 0) {
        bf16* out = (bf16*)outp;
        const int hh = col >> 6, d = col & 63;
#pragma unroll
        for (int i = 0; i < 4; i++) {
          int m = row0 + mi * 16 + i;
          int bb = m >> 12, t = m & 4095;
          out[(((size_t)(bb * 8 + hh) * 4096 + t) << 6) + d] =
              (bf16)(acc[mi][ni][i] * oscale);
        }
      } else {
        bf16* out = (bf16*)outp;
        const int hh = col >> 6, d = col & 63;
        int m0 = row0 + mi * 16;
        int bb = m0 >> 12, t0 = m0 & 4095;
        short4v pk;
#pragma unroll
        for (int i = 0; i < 4; i++) pk[i] = bfbits(acc[mi][ni][i]);
        *(short4v*)&out[(((size_t)(bb * 8 + hh) * 64 + d) << 12) + t0] = pk;
      }
    }
  }
}

// 0.125 * log2(e): folded into Q so attention scores are in exp2 domain.
#define QSCALE 0.18033688f

__global__ __launch_bounds__(256) void qkv_kernel(
    const bf16* __restrict__ cx, const bf16* __restrict__ cW,
    bf16* q, bf16* k, bf16* vt) {
  __shared__ __align__(16) bf16 As[128 * 64];
  __shared__ __align__(16) bf16 Bs[128 * 64];
  if (blockIdx.z == 0)      gemm_body<0, 128>(As, Bs, cx, cW, q, QSCALE);
  else if (blockIdx.z == 1) gemm_body<0, 128>(As, Bs, cx, cW + 262144, k, 1.0f);
  else                      gemm_body<2, 128>(As, Bs, cx, cW + 2 * 262144, vt, 1.0f);
}

__global__ __launch_bounds__(256) void proj_kernel(
    const bf16* __restrict__ y, const bf16* __restrict__ cWout,
    float* __restrict__ out) {
  __shared__ __align__(16) bf16 As[64 * 64];
  __shared__ __align__(16) bf16 Bs[128 * 64];
  gemm_body<1, 64>(As, Bs, y, cWout, out, 1.0f);
}

// ---------------------------------------------------------------------------
// Flash attention (causal), max-free exp2 softmax, swizzled LDS, in-register
// P (swapped QK^T + pre-permuted V in LDS).
// This revision:
//  - 8-wave blocks, SPLIT-K across two 4-wave groups: group 0 does kt
//    [0,S0), group 1 does kt [S0,qt], S0 = ceil((qt+1)/2). Partial (O,l)
//    over disjoint kt combine by plain addition (max-free softmax) via an
//    LDS reduce in the epilogue. Durations <= 33 steps (was 1..65).
//  - Grid 1024 blocks at 64KB LDS -> capacity 2 blocks/CU = 512 < grid:
//    hardware refill now load-balances; qt-descending order so the final
//    stragglers are the 1-step blocks. Steady 16 waves/CU (no drain tail).
//  - l via ones-MFMA: Lacc = P (.) 1 on the matrix pipe replaces 16 VALU
//    adds/iter AND lands l in the O-row register layout (no end shuffles).
// ---------------------------------------------------------------------------
__device__ __forceinline__ int lsw(int row, int col) {
  // swizzled element offset into a [rows][64] bf16 tile
  return (row << 6) + (col ^ ((row & 7) << 3));
}

template <bool DIAG>
__device__ __forceinline__ void attn_step(const bf16* __restrict__ Kc,
                                          const bf16* __restrict__ Vc,
                                          short8 qf0, short8 qf1, short8 ones,
                                          int wave, int lr, int quad,
                                          float4v& Lacc, float4v* O) {
  // QK^T swapped: S^T tile nc covers k-rows [16nc,16nc+16), cols q = lr.
  float4v S[4] = {};
#pragma unroll
  for (int nc = 0; nc < 4; nc++) {
    short8 kf0 = *(const short8*)&Kc[lsw(nc * 16 + lr, quad * 8)];
    short8 kf1 = *(const short8*)&Kc[lsw(nc * 16 + lr, 32 + quad * 8)];
    S[nc] = MFMA16(kf0, qf0, S[nc]);
    S[nc] = MFMA16(kf1, qf1, S[nc]);
  }

  // softmax (exp2 domain) + in-lane P pack (P[q=lr][k'=16nc+4quad+i]).
  short8 pf0, pf1;
#pragma unroll
  for (int nc = 0; nc < 4; nc++) {
#pragma unroll
    for (int i = 0; i < 4; i++) {
      float pv = exp2f(S[nc][i]);
      if (DIAG) {
        int kl = nc * 16 + quad * 4 + i;
        pv = (kl > wave * 16 + lr) ? 0.f : pv;
      }
      short bb = bfbits(pv);
      if (nc == 0)      pf0[i] = bb;
      else if (nc == 1) pf0[4 + i] = bb;
      else if (nc == 2) pf1[i] = bb;
      else              pf1[4 + i] = bb;
    }
  }

  // l row-sums on the MFMA pipe: Lacc[i] = l[q = wave*16 + quad*4 + i]
  // (B = ones broadcasts the row-sum across all n columns).
  Lacc = MFMA16(pf0, ones, Lacc);
  Lacc = MFMA16(pf1, ones, Lacc);

  // PV: V pre-permuted in LDS -> straight swizzled b128 reads.
#pragma unroll
  for (int nc = 0; nc < 4; nc++) {
    const int row = nc * 16 + lr;
    short8 vfa = *(const short8*)&Vc[lsw(row, quad * 8)];
    short8 vfb = *(const short8*)&Vc[lsw(row, 32 + quad * 8)];
    O[nc] = MFMA16(pf0, vfa, O[nc]);
    O[nc] = MFMA16(pf1, vfb, O[nc]);
  }
}

// permuted V staging: global cols [8s, 8s+8) of a row land in LDS columns
// {vA..vA+3, vA+8..vA+11} where vA = 32*(s>>2) + 16*(s&1) + 4*((s>>1)&1).
__device__ __forceinline__ void vstore_perm(bf16* Vb, int row, int vA,
                                            short8 rv) {
  short4v lo = __builtin_shufflevector(rv, rv, 0, 1, 2, 3);
  short4v hi = __builtin_shufflevector(rv, rv, 4, 5, 6, 7);
  *(short4v*)&Vb[lsw(row, vA)] = lo;
  *(short4v*)&Vb[lsw(row, vA + 8)] = hi;
}

__global__ __launch_bounds__(512, 4) void attn_kernel(const bf16* __restrict__ Qg,
                                                      const bf16* __restrict__ Kg,
                                                      const bf16* __restrict__ Vtg,
                                                      bf16* __restrict__ Y) {
  constexpr int T = 4096;
  // [group][dbuf][K=0/V=1][64*64] = 64 KB
  __shared__ __align__(16) bf16 KV[2][2][2][64 * 64];

  const int bx = blockIdx.x;           // 0..1023, longest (qt=63) first
  const int qt = 63 - (bx >> 4);
  const int hb = bx & 15;
  const int h = hb >> 1, b = hb & 1;
  const size_t ho = ((size_t)(b * 8 + h)) * T * 64;
  const bf16* Qh = Qg + ho;
  const bf16* Kh = Kg + ho;
  const bf16* Vth = Vtg + ho;

  const int tid = threadIdx.x;
  const int G = tid >> 8;              // k-split group
  const int t = tid & 255;
  const int wave = t >> 6, lane = t & 63;
  const int lr = lane & 15, quad = lane >> 4;

  const int S0 = (qt + 2) >> 1;        // group 0: kt 0..S0-1
  const int S1 = qt + 1 - S0;          // group 1: kt S0..qt (S1 <= S0)
  const int kbase = G ? S0 : 0;
  const int mysteps = G ? S1 : S0;

  bf16* const Kb0 = KV[G][0][0];
  bf16* const Kb1 = KV[G][1][0];
  bf16* const Vb0 = KV[G][0][1];
  bf16* const Vb1 = KV[G][1][1];

  // staging geometry (group-local): rows sr, sr+32, cols sc..sc+7
  const int sr = t >> 3;
  const int s8 = t & 7;
  const int sc = s8 * 8;
  const int vA = 32 * (s8 >> 2) + 16 * (s8 & 1) + 4 * ((s8 >> 1) & 1);
  const bf16* ksrc0 = Kh + (size_t)sr * 64 + sc;   // + kt*4096
  const bf16* ksrc1 = ksrc0 + 32 * 64;
  const bf16* vsrc0 = Vth + (size_t)sr * T + sc;   // + kt*64
  const bf16* vsrc1 = vsrc0 + (size_t)32 * T;
  const int d0 = lsw(sr, sc);
  const int d1 = lsw(sr + 32, sc);

  // issue first K/V tile loads early (land during Q staging)
  short8 rk0, rk1, rv0, rv1;
  if (mysteps > 0) {
    const size_t ko = (size_t)kbase * 4096;
    const size_t vo = (size_t)kbase * 64;
    rk0 = *(const short8*)(ksrc0 + ko);
    rk1 = *(const short8*)(ksrc1 + ko);
    rv0 = *(const short8*)(vsrc0 + vo);
    rv1 = *(const short8*)(vsrc1 + vo);
  }

  // Q staged ONCE by all 512 threads through group 0's Kb1 (free until the
  // end of step 0); both groups read their fragments before the loop.
  {
    int rr = tid >> 3, c = (tid & 7) * 8;
    *(short8*)&KV[0][1][0][lsw(rr, c)] =
        *(const short8*)&Qh[(size_t)(qt * 64 + rr) * 64 + c];
  }
  __syncthreads();
  short8 qf0 = *(const short8*)&KV[0][1][0][lsw(wave * 16 + lr, quad * 8)];
  short8 qf1 = *(const short8*)&KV[0][1][0][lsw(wave * 16 + lr, 32 + quad * 8)];
  if (mysteps > 0) {
    *(short8*)&Kb0[d0] = rk0;
    *(short8*)&Kb0[d1] = rk1;
    vstore_perm(Vb0, sr, vA, rv0);
    vstore_perm(Vb0, sr + 32, vA, rv1);
  }
  __syncthreads();  // qf reads done + both groups' buf 0 staged

  short8 ones;
#pragma unroll
  for (int j = 0; j < 8; j++) ones[j] = (short)0x3F80;  // bf16 1.0

  float4v O[4] = {};
  float4v Lacc = {};

  for (int s = 0; s < S0; s++) {
    const bool act = s < mysteps;
    const bool pf = s + 1 < mysteps;
    if (pf) {  // issue next tile's global loads before compute
      const size_t ko = (size_t)(kbase + s + 1) * 4096;
      const size_t vo = (size_t)(kbase + s + 1) * 64;
      rk0 = *(const short8*)(ksrc0 + ko);
      rk1 = *(const short8*)(ksrc1 + ko);
      rv0 = *(const short8*)(vsrc0 + vo);
      rv1 = *(const short8*)(vsrc1 + vo);
    }

    if (act) {
      const bf16* Kc = (s & 1) ? Kb1 : Kb0;
      const bf16* Vc = (s & 1) ? Vb1 : Vb0;
      const int kt = kbase + s;
      if (kt == qt) attn_step<true>(Kc, Vc, qf0, qf1, ones, wave, lr, quad, Lacc, O);
      else          attn_step<false>(Kc, Vc, qf0, qf1, ones, wave, lr, quad, Lacc, O);
    }

    if (pf) {  // store prefetched tile to the other buffer
      bf16* Kn = (s & 1) ? Kb0 : Kb1;
      bf16* Vn = (s & 1) ? Vb0 : Vb1;
      *(short8*)&Kn[d0] = rk0;
      *(short8*)&Kn[d1] = rk1;
      vstore_perm(Vn, sr, vA, rv0);
      vstore_perm(Vn, sr + 32, vA, rv1);
    }
    __syncthreads();  // single barrier per step (both groups, same count)
  }

  // ---- split-k combine: group 1 dumps partials into its own LDS region ----
  float* Op = (float*)&KV[1][0][0][0];   // 64x64 f32 = 16 KB
  float* Lp = Op + 64 * 64;              // 64 f32
  const int r0 = wave * 16 + quad * 4;
  if (G == 1 && S1 > 0) {
#pragma unroll
    for (int nc = 0; nc < 4; nc++)
#pragma unroll
      for (int i = 0; i < 4; i++)
        Op[(r0 + i) * 64 + nc * 16 + lr] = O[nc][i];
    if (lr == 0) {
#pragma unroll
      for (int i = 0; i < 4; i++) Lp[r0 + i] = Lacc[i];
    }
  }
  __syncthreads();
  if (G == 0) {
    float inv[4];
#pragma unroll
    for (int i = 0; i < 4; i++) {
      float lt = Lacc[i] + (S1 > 0 ? Lp[r0 + i] : 0.f);
      inv[i] = 1.f / lt;
    }
    const size_t yb = ((size_t)b * T + qt * 64 + r0) * 512 + h * 64;
#pragma unroll
    for (int nc = 0; nc < 4; nc++)
#pragma unroll
      for (int i = 0; i < 4; i++) {
        float o = O[nc][i] + (S1 > 0 ? Op[(r0 + i) * 64 + nc * 16 + lr] : 0.f);
        Y[yb + (size_t)i * 512 + nc * 16 + lr] = (bf16)(o * inv[i]);
      }
  }
}

// ---------------------------------------------------------------------------
extern "C" void kernel_launch(void* const* d_in, const int* in_sizes, int n_in,
                              void* d_out, int out_size, void* d_ws, size_t ws_size,
                              hipStream_t stream) {
  (void)out_size; (void)ws_size;
  // Interface verified R9: dict-order slots, fp32 in, x=[B,T,C], fp32 out.
  const int NX = 8192 * 512;
  int xi = 0;
  for (int i = 0; i < n_in; i++)
    if (in_sizes[i] == NX) { xi = i; break; }
  const float* x = (const float*)d_in[xi];
  const float* wsrc[4];
  int wn = 0;
  for (int i = 0; i < n_in && wn < 4; i++)
    if (i != xi) wsrc[wn++] = (const float*)d_in[i];

  bf16* ws = (bf16*)d_ws;
  const size_t HE = (size_t)NX;
  bf16* q  = ws;                 // 8 MB
  bf16* k  = q + HE;             // 8 MB
  bf16* yx = k + HE;             // 8 MB: bf16 x during qkv, y after attn
  bf16* cw = yx + HE;            // 2 MB (4 weights)  -> 26 MB ws total
  bf16* vt = (bf16*)d_out;       // V^T staged in d_out, consumed before proj
  float* out = (float*)d_out;

  conv_all<<<2560, 256, 0, stream>>>(x, wsrc[0], wsrc[1], wsrc[2], wsrc[3],
                                     yx, cw);
  qkv_kernel<<<dim3(64, 4, 3), 256, 0, stream>>>(yx, cw, q, k, vt);
  attn_kernel<<<1024, 512, 0, stream>>>(q, k, vt, yx);
  proj_kernel<<<dim3(128, 4), 256, 0, stream>>>(yx, cw + 3 * 262144, out);
}

// Round 7
// 164.943 us; speedup vs baseline: 1.0036x; 1.0036x over previous
//
#include <hip/hip_runtime.h>
#include <hip/hip_bf16.h>
#include <math.h>
#include <stdint.h>

using bf16 = __hip_bfloat16;
typedef __attribute__((ext_vector_type(8))) short short8;
typedef __attribute__((ext_vector_type(4))) short short4v;
typedef __attribute__((ext_vector_type(4))) float float4v;

#define MFMA16(a, b, c) __builtin_amdgcn_mfma_f32_16x16x32_bf16(a, b, c, 0, 0, 0)

__device__ __forceinline__ short bfbits(float f) {
  bf16 h = (bf16)f;
  return *(short*)&h;
}

__device__ __forceinline__ short8 ld_cvt8(const float* p) {
  union { float4v v[2]; float f[8]; } u;
  u.v[0] = *(const float4v*)p;
  u.v[1] = *(const float4v*)(p + 4);
  short8 r;
#pragma unroll
  for (int j = 0; j < 8; j++) r[j] = bfbits(u.f[j]);
  return r;
}

// global -> LDS direct copy, 16B per lane. LDS dest = uniform base + lane*16.
__device__ __forceinline__ void gload16(const bf16* g, bf16* l) {
  __builtin_amdgcn_global_load_lds(
      (const __attribute__((address_space(1))) void*)g,
      (__attribute__((address_space(3))) void*)l, 16, 0, 0);
}

// ---------------------------------------------------------------------------
// One-shot fp32 -> bf16 conversion of x and the 4 weights.
// Concatenated elem space: [x:4194304][Wq,Wk,Wv,Wout: 262144 each].
// ---------------------------------------------------------------------------
__global__ __launch_bounds__(256) void conv_all(
    const float* __restrict__ x, const float* __restrict__ w0,
    const float* __restrict__ w1, const float* __restrict__ w2,
    const float* __restrict__ w3, bf16* __restrict__ cx,
    bf16* __restrict__ cw) {
  size_t gid = ((size_t)blockIdx.x * 256 + threadIdx.x) * 8;
  const float* src;
  bf16* dst;
  size_t off;
  if (gid < 4194304) {
    src = x; dst = cx; off = gid;
  } else {
    size_t r = gid - 4194304;
    int wi = (int)(r >> 18);
    src = wi == 0 ? w0 : wi == 1 ? w1 : wi == 2 ? w2 : w3;
    dst = cw + ((size_t)wi << 18);
    off = r & 262143;
  }
  *(short8*)(dst + off) = ld_cvt8(src + off);
}

// ---------------------------------------------------------------------------
// GEMM (NT, all-bf16): C[MTx128] tile of A[M,512] * W[N,512]^T.
// m97-structure staging: global_load_lds width=16 into linear [rows][64] LDS,
// XOR-swizzled on BOTH sides (pre-swizzled global source column + swizzled
// ds_read_b128), BK=64 (2 MFMA sub-steps per barrier pair, 8 k-steps).
// MODE 0: out[b,h,t,d] bf16 scaled (Q,K). MODE 1: out[m,n] fp32 (proj).
// MODE 2: out[b,h,d,t] bf16 (V^T).
// ---------------------------------------------------------------------------
template <int MODE, int MT>
__device__ __forceinline__ void gemm_body(bf16* As, bf16* Bs,
                                          const bf16* __restrict__ A,
                                          const bf16* __restrict__ W,
                                          void* __restrict__ outp,
                                          float oscale) {
  constexpr int MI = MT / 32;
  const int bm = blockIdx.x * MT, bn = blockIdx.y * 128;
  const int tid = threadIdx.x;
  const int lane = tid & 63;
  const int wave = tid >> 6;
  const int lr = lane & 15, quad = lane >> 4;
  const int wm = (wave & 1) * (MT / 2), wn = (wave >> 1) * 64;

  const int srow = lane >> 3;
  const int scl = (lane & 7) ^ (srow & 7);
  const int rsw = lr & 7;

  float4v acc[MI][4] = {};

  for (int k0 = 0; k0 < 512; k0 += 64) {
    __syncthreads();  // previous sub-step's LDS reads complete
#pragma unroll
    for (int j = 0; j < MT / 32; j++) {  // A: MT/8 instrs, MT/32 per wave
      const int m = wave + 4 * j;        // 8-row group index
      gload16(&A[(size_t)(bm + 8 * m + srow) * 512 + k0 + scl * 8],
              &As[(8 * m) * 64]);
    }
#pragma unroll
    for (int j = 0; j < 4; j++) {        // B: 16 instrs, 4 per wave
      const int m = wave + 4 * j;
      gload16(&W[(size_t)(bn + 8 * m + srow) * 512 + k0 + scl * 8],
              &Bs[(8 * m) * 64]);
    }
    __syncthreads();  // barrier drains vmcnt: staged tile visible
#pragma unroll
    for (int kk = 0; kk < 2; kk++) {
      short8 af[MI], bfv[4];
#pragma unroll
      for (int i = 0; i < MI; i++)
        af[i] = *(const short8*)
            &As[(wm + i * 16 + lr) * 64 + ((4 * kk + quad) ^ rsw) * 8];
#pragma unroll
      for (int i = 0; i < 4; i++)
        bfv[i] = *(const short8*)
            &Bs[(wn + i * 16 + lr) * 64 + ((4 * kk + quad) ^ rsw) * 8];
#pragma unroll
      for (int mi = 0; mi < MI; mi++)
#pragma unroll
        for (int ni = 0; ni < 4; ni++)
          acc[mi][ni] = MFMA16(af[mi], bfv[ni], acc[mi][ni]);
    }
  }

  const int row0 = bm + wm + quad * 4;
  const int col0 = bn + wn + lr;
#pragma unroll
  for (int mi = 0; mi < MI; mi++) {
#pragma unroll
    for (int ni = 0; ni < 4; ni++) {
      const int col = col0 + ni * 16;
      if (MODE == 1) {
        float* out = (float*)outp;
#pragma unroll
        for (int i = 0; i < 4; i++) {
          int m = row0 + mi * 16 + i;
          out[(size_t)m * 512 + col] = acc[mi][ni][i];
        }
      } else if (MODE == 0) {
        bf16* out = (bf16*)outp;
        const int hh = col >> 6, d = col & 63;
#pragma unroll
        for (int i = 0; i < 4; i++) {
          int m = row0 + mi * 16 + i;
          int bb = m >> 12, t = m & 4095;
          out[(((size_t)(bb * 8 + hh) * 4096 + t) << 6) + d] =
              (bf16)(acc[mi][ni][i] * oscale);
        }
      } else {
        bf16* out = (bf16*)outp;
        const int hh = col >> 6, d = col & 63;
        int m0 = row0 + mi * 16;
        int bb = m0 >> 12, t0 = m0 & 4095;
        short4v pk;
#pragma unroll
        for (int i = 0; i < 4; i++) pk[i] = bfbits(acc[mi][ni][i]);
        *(short4v*)&out[(((size_t)(bb * 8 + hh) * 64 + d) << 12) + t0] = pk;
      }
    }
  }
}

// 0.125 * log2(e): folded into Q so attention scores are in exp2 domain.
#define QSCALE 0.18033688f

__global__ __launch_bounds__(256) void qkv_kernel(
    const bf16* __restrict__ cx, const bf16* __restrict__ cW,
    bf16* q, bf16* k, bf16* vt) {
  __shared__ __align__(16) bf16 As[128 * 64];
  __shared__ __align__(16) bf16 Bs[128 * 64];
  if (blockIdx.z == 0)      gemm_body<0, 128>(As, Bs, cx, cW, q, QSCALE);
  else if (blockIdx.z == 1) gemm_body<0, 128>(As, Bs, cx, cW + 262144, k, 1.0f);
  else                      gemm_body<2, 128>(As, Bs, cx, cW + 2 * 262144, vt, 1.0f);
}

__global__ __launch_bounds__(256) void proj_kernel(
    const bf16* __restrict__ y, const bf16* __restrict__ cWout,
    float* __restrict__ out) {
  __shared__ __align__(16) bf16 As[64 * 64];
  __shared__ __align__(16) bf16 Bs[128 * 64];
  gemm_body<1, 64>(As, Bs, y, cWout, out, 1.0f);
}

// ---------------------------------------------------------------------------
// Flash attention (causal), max-free exp2 softmax, swizzled LDS, in-register
// P (swapped QK^T + pre-permuted V in LDS), split-K 2 groups, ones-MFMA l.
// This revision: 32 q-rows PER WAVE (two Q fragment sets per wave). One set
// of K/V fragment reads (16 ds_read_b128) now feeds BOTH sets' MFMAs ->
// LDS fragment traffic per q-row halves (the est. ~59%-busy LDS pipe was
// co-dominant with VALU). Blocks shrink 512->256 threads (2 waves/group);
// grid/LDS/refill structure unchanged (1024 blocks, 64KB, 2 blocks/CU).
// Each wave also gains a second independent S/O chain (ILP at same waves).
// ---------------------------------------------------------------------------
__device__ __forceinline__ int lsw(int row, int col) {
  // swizzled element offset into a [rows][64] bf16 tile
  return (row << 6) + (col ^ ((row & 7) << 3));
}

template <bool DIAG>
__device__ __forceinline__ void attn_step2(const bf16* __restrict__ Kc,
                                           const bf16* __restrict__ Vc,
                                           const short8 (&qf)[2][2],
                                           short8 ones, int qb /* 32*wave */,
                                           int lr, int quad,
                                           float4v (&Lacc)[2],
                                           float4v (&O)[2][4]) {
  // QK^T swapped: S^T[s] tile nc covers k-rows [16nc,16nc+16), cols
  // q = qb + 16s + lr. K frags shared across both q-sets.
  float4v S[2][4] = {};
#pragma unroll
  for (int nc = 0; nc < 4; nc++) {
    short8 kf0 = *(const short8*)&Kc[lsw(nc * 16 + lr, quad * 8)];
    short8 kf1 = *(const short8*)&Kc[lsw(nc * 16 + lr, 32 + quad * 8)];
#pragma unroll
    for (int s = 0; s < 2; s++) {
      S[s][nc] = MFMA16(kf0, qf[s][0], S[s][nc]);
      S[s][nc] = MFMA16(kf1, qf[s][1], S[s][nc]);
    }
  }

  // softmax (exp2 domain) + in-lane P pack (P[q][k'=16nc+4quad+i]).
  short8 pf[2][2];
#pragma unroll
  for (int s = 0; s < 2; s++) {
#pragma unroll
    for (int nc = 0; nc < 4; nc++) {
#pragma unroll
      for (int i = 0; i < 4; i++) {
        float pv = exp2f(S[s][nc][i]);
        if (DIAG) {
          int kl = nc * 16 + quad * 4 + i;
          pv = (kl > qb + 16 * s + lr) ? 0.f : pv;
        }
        short bb = bfbits(pv);
        if (nc == 0)      pf[s][0][i] = bb;
        else if (nc == 1) pf[s][0][4 + i] = bb;
        else if (nc == 2) pf[s][1][i] = bb;
        else              pf[s][1][4 + i] = bb;
      }
    }
    // l row-sums on the MFMA pipe (lands in O-row register layout).
    Lacc[s] = MFMA16(pf[s][0], ones, Lacc[s]);
    Lacc[s] = MFMA16(pf[s][1], ones, Lacc[s]);
  }

  // PV: V pre-permuted in LDS -> straight swizzled b128 reads, shared
  // across both q-sets.
#pragma unroll
  for (int nc = 0; nc < 4; nc++) {
    short8 vfa = *(const short8*)&Vc[lsw(nc * 16 + lr, quad * 8)];
    short8 vfb = *(const short8*)&Vc[lsw(nc * 16 + lr, 32 + quad * 8)];
#pragma unroll
    for (int s = 0; s < 2; s++) {
      O[s][nc] = MFMA16(pf[s][0], vfa, O[s][nc]);
      O[s][nc] = MFMA16(pf[s][1], vfb, O[s][nc]);
    }
  }
}

// permuted V staging: global cols [8s, 8s+8) of a row land in LDS columns
// {vA..vA+3, vA+8..vA+11} where vA = 32*(s>>2) + 16*(s&1) + 4*((s>>1)&1).
__device__ __forceinline__ void vstore_perm(bf16* Vb, int row, int vA,
                                            short8 rv) {
  short4v lo = __builtin_shufflevector(rv, rv, 0, 1, 2, 3);
  short4v hi = __builtin_shufflevector(rv, rv, 4, 5, 6, 7);
  *(short4v*)&Vb[lsw(row, vA)] = lo;
  *(short4v*)&Vb[lsw(row, vA + 8)] = hi;
}

__global__ __launch_bounds__(256, 2) void attn_kernel(const bf16* __restrict__ Qg,
                                                      const bf16* __restrict__ Kg,
                                                      const bf16* __restrict__ Vtg,
                                                      bf16* __restrict__ Y) {
  constexpr int T = 4096;
  // [group][dbuf][K=0/V=1][64*64] = 64 KB
  __shared__ __align__(16) bf16 KV[2][2][2][64 * 64];

  const int bx = blockIdx.x;           // 0..1023, longest (qt=63) first
  const int qt = 63 - (bx >> 4);
  const int hb = bx & 15;
  const int h = hb >> 1, b = hb & 1;
  const size_t ho = ((size_t)(b * 8 + h)) * T * 64;
  const bf16* Qh = Qg + ho;
  const bf16* Kh = Kg + ho;
  const bf16* Vth = Vtg + ho;

  const int tid = threadIdx.x;
  const int G = tid >> 7;              // k-split group (2 waves each)
  const int t = tid & 127;
  const int wave = t >> 6, lane = t & 63;
  const int lr = lane & 15, quad = lane >> 4;
  const int qb = wave * 32;            // this wave's 32-q-row base

  const int S0 = (qt + 2) >> 1;        // group 0: kt 0..S0-1
  const int S1 = qt + 1 - S0;          // group 1: kt S0..qt (S1 <= S0)
  const int kbase = G ? S0 : 0;
  const int mysteps = G ? S1 : S0;

  bf16* const Kb0 = KV[G][0][0];
  bf16* const Kb1 = KV[G][1][0];
  bf16* const Vb0 = KV[G][0][1];
  bf16* const Vb1 = KV[G][1][1];

  // staging geometry (group-local, 128 threads): rows sr+16j (j=0..3),
  // cols sc..sc+7
  const int sr = t >> 3;
  const int s8 = t & 7;
  const int sc = s8 * 8;
  const int vA = 32 * (s8 >> 2) + 16 * (s8 & 1) + 4 * ((s8 >> 1) & 1);
  const bf16* ksrc[4];
  const bf16* vsrc[4];
  int dK[4];
#pragma unroll
  for (int j = 0; j < 4; j++) {
    ksrc[j] = Kh + (size_t)(sr + 16 * j) * 64 + sc;   // + kt*4096
    vsrc[j] = Vth + (size_t)(sr + 16 * j) * T + sc;   // + kt*64
    dK[j] = lsw(sr + 16 * j, sc);
  }

  // issue first K/V tile loads early (land during Q staging)
  short8 rk[4], rv[4];
  if (mysteps > 0) {
    const size_t ko = (size_t)kbase * 4096;
    const size_t vo = (size_t)kbase * 64;
#pragma unroll
    for (int j = 0; j < 4; j++) {
      rk[j] = *(const short8*)(ksrc[j] + ko);
      rv[j] = *(const short8*)(vsrc[j] + vo);
    }
  }

  // Q staged ONCE by all 256 threads through group 0's Kb1 (free until the
  // end of step 0); both groups read their fragments before the loop.
#pragma unroll
  for (int j = 0; j < 2; j++) {
    int rr = (tid >> 3) + 32 * j, c = (tid & 7) * 8;
    *(short8*)&KV[0][1][0][lsw(rr, c)] =
        *(const short8*)&Qh[(size_t)(qt * 64 + rr) * 64 + c];
  }
  __syncthreads();
  short8 qf[2][2];
#pragma unroll
  for (int s = 0; s < 2; s++) {
    qf[s][0] = *(const short8*)&KV[0][1][0][lsw(qb + 16 * s + lr, quad * 8)];
    qf[s][1] = *(const short8*)&KV[0][1][0][lsw(qb + 16 * s + lr, 32 + quad * 8)];
  }
  if (mysteps > 0) {
#pragma unroll
    for (int j = 0; j < 4; j++) {
      *(short8*)&Kb0[dK[j]] = rk[j];
      vstore_perm(Vb0, sr + 16 * j, vA, rv[j]);
    }
  }
  __syncthreads();  // qf reads done + both groups' buf 0 staged

  short8 ones;
#pragma unroll
  for (int j = 0; j < 8; j++) ones[j] = (short)0x3F80;  // bf16 1.0

  float4v O[2][4] = {};
  float4v Lacc[2] = {};

  for (int s = 0; s < S0; s++) {
    const bool act = s < mysteps;
    const bool pf = s + 1 < mysteps;
    if (pf) {  // issue next tile's global loads before compute
      const size_t ko = (size_t)(kbase + s + 1) * 4096;
      const size_t vo = (size_t)(kbase + s + 1) * 64;
#pragma unroll
      for (int j = 0; j < 4; j++) {
        rk[j] = *(const short8*)(ksrc[j] + ko);
        rv[j] = *(const short8*)(vsrc[j] + vo);
      }
    }

    if (act) {
      const bf16* Kc = (s & 1) ? Kb1 : Kb0;
      const bf16* Vc = (s & 1) ? Vb1 : Vb0;
      const int kt = kbase + s;
      if (kt == qt) attn_step2<true>(Kc, Vc, qf, ones, qb, lr, quad, Lacc, O);
      else          attn_step2<false>(Kc, Vc, qf, ones, qb, lr, quad, Lacc, O);
    }

    if (pf) {  // store prefetched tile to the other buffer
      bf16* Kn = (s & 1) ? Kb0 : Kb1;
      bf16* Vn = (s & 1) ? Vb0 : Vb1;
#pragma unroll
      for (int j = 0; j < 4; j++) {
        *(short8*)&Kn[dK[j]] = rk[j];
        vstore_perm(Vn, sr + 16 * j, vA, rv[j]);
      }
    }
    __syncthreads();  // single barrier per step (both groups, same count)
  }

  // ---- split-k combine: group 1 dumps partials into its own LDS region ----
  float* Op = (float*)&KV[1][0][0][0];   // 64x64 f32 = 16 KB (Kb0+Vb0 of G1)
  float* Lp = (float*)&KV[1][1][0][0];   // 64 f32
  if (G == 1 && S1 > 0) {
#pragma unroll
    for (int s = 0; s < 2; s++) {
      const int r0 = qb + 16 * s + quad * 4;
#pragma unroll
      for (int nc = 0; nc < 4; nc++)
#pragma unroll
        for (int i = 0; i < 4; i++)
          Op[(r0 + i) * 64 + nc * 16 + lr] = O[s][nc][i];
      if (lr == 0) {
#pragma unroll
        for (int i = 0; i < 4; i++) Lp[r0 + i] = Lacc[s][i];
      }
    }
  }
  __syncthreads();
  if (G == 0) {
#pragma unroll
    for (int s = 0; s < 2; s++) {
      const int r0 = qb + 16 * s + quad * 4;
      float inv[4];
#pragma unroll
      for (int i = 0; i < 4; i++) {
        float lt = Lacc[s][i] + (S1 > 0 ? Lp[r0 + i] : 0.f);
        inv[i] = 1.f / lt;
      }
      const size_t yb = ((size_t)b * T + qt * 64 + r0) * 512 + h * 64;
#pragma unroll
      for (int nc = 0; nc < 4; nc++)
#pragma unroll
        for (int i = 0; i < 4; i++) {
          float o = O[s][nc][i] +
                    (S1 > 0 ? Op[(r0 + i) * 64 + nc * 16 + lr] : 0.f);
          Y[yb + (size_t)i * 512 + nc * 16 + lr] = (bf16)(o * inv[i]);
        }
    }
  }
}

// ---------------------------------------------------------------------------
extern "C" void kernel_launch(void* const* d_in, const int* in_sizes, int n_in,
                              void* d_out, int out_size, void* d_ws, size_t ws_size,
                              hipStream_t stream) {
  (void)out_size; (void)ws_size;
  // Interface verified R9: dict-order slots, fp32 in, x=[B,T,C], fp32 out.
  const int NX = 8192 * 512;
  int xi = 0;
  for (int i = 0; i < n_in; i++)
    if (in_sizes[i] == NX) { xi = i; break; }
  const float* x = (const float*)d_in[xi];
  const float* wsrc[4];
  int wn = 0;
  for (int i = 0; i < n_in && wn < 4; i++)
    if (i != xi) wsrc[wn++] = (const float*)d_in[i];

  bf16* ws = (bf16*)d_ws;
  const size_t HE = (size_t)NX;
  bf16* q  = ws;                 // 8 MB
  bf16* k  = q + HE;             // 8 MB
  bf16* yx = k + HE;             // 8 MB: bf16 x during qkv, y after attn
  bf16* cw = yx + HE;            // 2 MB (4 weights)  -> 26 MB ws total
  bf16* vt = (bf16*)d_out;       // V^T staged in d_out, consumed before proj
  float* out = (float*)d_out;

  conv_all<<<2560, 256, 0, stream>>>(x, wsrc[0], wsrc[1], wsrc[2], wsrc[3],
                                     yx, cw);
  qkv_kernel<<<dim3(64, 4, 3), 256, 0, stream>>>(yx, cw, q, k, vt);
  attn_kernel<<<1024, 256, 0, stream>>>(q, k, vt, yx);
  proj_kernel<<<dim3(128, 4), 256, 0, stream>>>(yx, cw + 3 * 262144, out);
}

// Round 8
// 161.491 us; speedup vs baseline: 1.0251x; 1.0214x over previous
//
#include <hip/hip_runtime.h>
#include <hip/hip_bf16.h>
#include <math.h>
#include <stdint.h>

using bf16 = __hip_bfloat16;
typedef __attribute__((ext_vector_type(8))) short short8;
typedef __attribute__((ext_vector_type(4))) short short4v;
typedef __attribute__((ext_vector_type(4))) float float4v;

#define MFMA16(a, b, c) __builtin_amdgcn_mfma_f32_16x16x32_bf16(a, b, c, 0, 0, 0)

__device__ __forceinline__ short bfbits(float f) {
  bf16 h = (bf16)f;
  return *(short*)&h;
}

__device__ __forceinline__ short8 ld_cvt8(const float* p) {
  union { float4v v[2]; float f[8]; } u;
  u.v[0] = *(const float4v*)p;
  u.v[1] = *(const float4v*)(p + 4);
  short8 r;
#pragma unroll
  for (int j = 0; j < 8; j++) r[j] = bfbits(u.f[j]);
  return r;
}

// global -> LDS direct copy, 16B per lane. LDS dest = uniform base + lane*16.
__device__ __forceinline__ void gload16(const bf16* g, bf16* l) {
  __builtin_amdgcn_global_load_lds(
      (const __attribute__((address_space(1))) void*)g,
      (__attribute__((address_space(3))) void*)l, 16, 0, 0);
}

// ---------------------------------------------------------------------------
// One-shot fp32 -> bf16 conversion of x and the 4 weights.
// Concatenated elem space: [x:4194304][Wq,Wk,Wv,Wout: 262144 each].
// ---------------------------------------------------------------------------
__global__ __launch_bounds__(256) void conv_all(
    const float* __restrict__ x, const float* __restrict__ w0,
    const float* __restrict__ w1, const float* __restrict__ w2,
    const float* __restrict__ w3, bf16* __restrict__ cx,
    bf16* __restrict__ cw) {
  size_t gid = ((size_t)blockIdx.x * 256 + threadIdx.x) * 8;
  const float* src;
  bf16* dst;
  size_t off;
  if (gid < 4194304) {
    src = x; dst = cx; off = gid;
  } else {
    size_t r = gid - 4194304;
    int wi = (int)(r >> 18);
    src = wi == 0 ? w0 : wi == 1 ? w1 : wi == 2 ? w2 : w3;
    dst = cw + ((size_t)wi << 18);
    off = r & 262143;
  }
  *(short8*)(dst + off) = ld_cvt8(src + off);
}

// ---------------------------------------------------------------------------
// GEMM (NT, all-bf16): C[MTx128] tile of A[M,512] * W[N,512]^T.
// m97-structure staging: global_load_lds width=16 into linear [rows][64] LDS,
// XOR-swizzled on BOTH sides (pre-swizzled global source column + swizzled
// ds_read_b128), BK=64 (2 MFMA sub-steps per barrier pair, 8 k-steps).
// MODE 0: out[b,h,t,d] bf16 scaled (Q,K). MODE 1: out[m,n] fp32 (proj).
// MODE 2: out[b,h,d,t] bf16 (V^T).
// ---------------------------------------------------------------------------
template <int MODE, int MT>
__device__ __forceinline__ void gemm_body(bf16* As, bf16* Bs,
                                          const bf16* __restrict__ A,
                                          const bf16* __restrict__ W,
                                          void* __restrict__ outp,
                                          float oscale) {
  constexpr int MI = MT / 32;
  const int bm = blockIdx.x * MT, bn = blockIdx.y * 128;
  const int tid = threadIdx.x;
  const int lane = tid & 63;
  const int wave = tid >> 6;
  const int lr = lane & 15, quad = lane >> 4;
  const int wm = (wave & 1) * (MT / 2), wn = (wave >> 1) * 64;

  const int srow = lane >> 3;
  const int scl = (lane & 7) ^ (srow & 7);
  const int rsw = lr & 7;

  float4v acc[MI][4] = {};

  for (int k0 = 0; k0 < 512; k0 += 64) {
    __syncthreads();  // previous sub-step's LDS reads complete
#pragma unroll
    for (int j = 0; j < MT / 32; j++) {  // A: MT/8 instrs, MT/32 per wave
      const int m = wave + 4 * j;        // 8-row group index
      gload16(&A[(size_t)(bm + 8 * m + srow) * 512 + k0 + scl * 8],
              &As[(8 * m) * 64]);
    }
#pragma unroll
    for (int j = 0; j < 4; j++) {        // B: 16 instrs, 4 per wave
      const int m = wave + 4 * j;
      gload16(&W[(size_t)(bn + 8 * m + srow) * 512 + k0 + scl * 8],
              &Bs[(8 * m) * 64]);
    }
    __syncthreads();  // barrier drains vmcnt: staged tile visible
#pragma unroll
    for (int kk = 0; kk < 2; kk++) {
      short8 af[MI], bfv[4];
#pragma unroll
      for (int i = 0; i < MI; i++)
        af[i] = *(const short8*)
            &As[(wm + i * 16 + lr) * 64 + ((4 * kk + quad) ^ rsw) * 8];
#pragma unroll
      for (int i = 0; i < 4; i++)
        bfv[i] = *(const short8*)
            &Bs[(wn + i * 16 + lr) * 64 + ((4 * kk + quad) ^ rsw) * 8];
#pragma unroll
      for (int mi = 0; mi < MI; mi++)
#pragma unroll
        for (int ni = 0; ni < 4; ni++)
          acc[mi][ni] = MFMA16(af[mi], bfv[ni], acc[mi][ni]);
    }
  }

  const int row0 = bm + wm + quad * 4;
  const int col0 = bn + wn + lr;
#pragma unroll
  for (int mi = 0; mi < MI; mi++) {
#pragma unroll
    for (int ni = 0; ni < 4; ni++) {
      const int col = col0 + ni * 16;
      if (MODE == 1) {
        float* out = (float*)outp;
#pragma unroll
        for (int i = 0; i < 4; i++) {
          int m = row0 + mi * 16 + i;
          out[(size_t)m * 512 + col] = acc[mi][ni][i];
        }
      } else if (MODE == 0) {
        bf16* out = (bf16*)outp;
        const int hh = col >> 6, d = col & 63;
#pragma unroll
        for (int i = 0; i < 4; i++) {
          int m = row0 + mi * 16 + i;
          int bb = m >> 12, t = m & 4095;
          out[(((size_t)(bb * 8 + hh) * 4096 + t) << 6) + d] =
              (bf16)(acc[mi][ni][i] * oscale);
        }
      } else {
        bf16* out = (bf16*)outp;
        const int hh = col >> 6, d = col & 63;
        int m0 = row0 + mi * 16;
        int bb = m0 >> 12, t0 = m0 & 4095;
        short4v pk;
#pragma unroll
        for (int i = 0; i < 4; i++) pk[i] = bfbits(acc[mi][ni][i]);
        *(short4v*)&out[(((size_t)(bb * 8 + hh) * 64 + d) << 12) + t0] = pk;
      }
    }
  }
}

// 0.125 * log2(e): folded into Q so attention scores are in exp2 domain.
#define QSCALE 0.18033688f

__global__ __launch_bounds__(256) void qkv_kernel(
    const bf16* __restrict__ cx, const bf16* __restrict__ cW,
    bf16* q, bf16* k, bf16* vt) {
  __shared__ __align__(16) bf16 As[128 * 64];
  __shared__ __align__(16) bf16 Bs[128 * 64];
  if (blockIdx.z == 0)      gemm_body<0, 128>(As, Bs, cx, cW, q, QSCALE);
  else if (blockIdx.z == 1) gemm_body<0, 128>(As, Bs, cx, cW + 262144, k, 1.0f);
  else                      gemm_body<2, 128>(As, Bs, cx, cW + 2 * 262144, vt, 1.0f);
}

__global__ __launch_bounds__(256) void proj_kernel(
    const bf16* __restrict__ y, const bf16* __restrict__ cWout,
    float* __restrict__ out) {
  __shared__ __align__(16) bf16 As[64 * 64];
  __shared__ __align__(16) bf16 Bs[128 * 64];
  gemm_body<1, 64>(As, Bs, y, cWout, out, 1.0f);
}

// ---------------------------------------------------------------------------
// Flash attention (causal), max-free exp2 softmax, swizzled LDS, in-register
// P (swapped QK^T + pre-permuted V in LDS), split-K 2 groups, ones-MFMA l.
// This revision: UNIFORM-DURATION blocks via diagonal q-tile PAIRING.
// Block handles q-tiles A=p and B=63-p: total causal work (p+1)+(64-p)=65
// kt-tiles for EVERY p. Split between the 2 groups -> group0 always 33
// steps, group1 always 32. Grid 512 blocks x 64KB LDS = exactly 2
// blocks/CU, all resident t=0, all CUs finish together (R6's 36% occupancy
// was refill granularity + drain tail on 1024 variable-length blocks).
// K/V staging shared by the pair (same head); per-step cost unchanged.
// ---------------------------------------------------------------------------
__device__ __forceinline__ int lsw(int row, int col) {
  // swizzled element offset into a [rows][64] bf16 tile
  return (row << 6) + (col ^ ((row & 7) << 3));
}

template <bool DIAG>
__device__ __forceinline__ void attn_step(const bf16* __restrict__ Kc,
                                          const bf16* __restrict__ Vc,
                                          short8 qf0, short8 qf1, short8 ones,
                                          int wave, int lr, int quad,
                                          float4v& Lacc, float4v* O) {
  // QK^T swapped: S^T tile nc covers k-rows [16nc,16nc+16), cols q = lr.
  float4v S[4] = {};
#pragma unroll
  for (int nc = 0; nc < 4; nc++) {
    short8 kf0 = *(const short8*)&Kc[lsw(nc * 16 + lr, quad * 8)];
    short8 kf1 = *(const short8*)&Kc[lsw(nc * 16 + lr, 32 + quad * 8)];
    S[nc] = MFMA16(kf0, qf0, S[nc]);
    S[nc] = MFMA16(kf1, qf1, S[nc]);
  }

  // softmax (exp2 domain) + in-lane P pack (P[q=lr][k'=16nc+4quad+i]).
  short8 pf0, pf1;
#pragma unroll
  for (int nc = 0; nc < 4; nc++) {
#pragma unroll
    for (int i = 0; i < 4; i++) {
      float pv = exp2f(S[nc][i]);
      if (DIAG) {
        int kl = nc * 16 + quad * 4 + i;
        pv = (kl > wave * 16 + lr) ? 0.f : pv;
      }
      short bb = bfbits(pv);
      if (nc == 0)      pf0[i] = bb;
      else if (nc == 1) pf0[4 + i] = bb;
      else if (nc == 2) pf1[i] = bb;
      else              pf1[4 + i] = bb;
    }
  }

  // l row-sums on the MFMA pipe: Lacc[i] = l[q = wave*16 + quad*4 + i].
  Lacc = MFMA16(pf0, ones, Lacc);
  Lacc = MFMA16(pf1, ones, Lacc);

  // PV: V pre-permuted in LDS -> straight swizzled b128 reads.
#pragma unroll
  for (int nc = 0; nc < 4; nc++) {
    const int row = nc * 16 + lr;
    short8 vfa = *(const short8*)&Vc[lsw(row, quad * 8)];
    short8 vfb = *(const short8*)&Vc[lsw(row, 32 + quad * 8)];
    O[nc] = MFMA16(pf0, vfa, O[nc]);
    O[nc] = MFMA16(pf1, vfb, O[nc]);
  }
}

// permuted V staging: global cols [8s, 8s+8) of a row land in LDS columns
// {vA..vA+3, vA+8..vA+11} where vA = 32*(s>>2) + 16*(s&1) + 4*((s>>1)&1).
__device__ __forceinline__ void vstore_perm(bf16* Vb, int row, int vA,
                                            short8 rv) {
  short4v lo = __builtin_shufflevector(rv, rv, 0, 1, 2, 3);
  short4v hi = __builtin_shufflevector(rv, rv, 4, 5, 6, 7);
  *(short4v*)&Vb[lsw(row, vA)] = lo;
  *(short4v*)&Vb[lsw(row, vA + 8)] = hi;
}

__global__ __launch_bounds__(512, 4) void attn_kernel(const bf16* __restrict__ Qg,
                                                      const bf16* __restrict__ Kg,
                                                      const bf16* __restrict__ Vtg,
                                                      bf16* __restrict__ Y) {
  constexpr int T = 4096;
  // [group][dbuf][K=0/V=1][64*64] = 64 KB
  __shared__ __align__(16) bf16 KV[2][2][2][64 * 64];

  const int bx = blockIdx.x;           // 0..511
  const int p = bx >> 4;               // pair index: q-tiles p and 63-p
  const int pB = 63 - p;
  const int hb = bx & 15;
  const int h = hb >> 1, b = hb & 1;
  const size_t ho = ((size_t)(b * 8 + h)) * T * 64;
  const bf16* Qh = Qg + ho;
  const bf16* Kh = Kg + ho;
  const bf16* Vth = Vtg + ho;

  const int tid = threadIdx.x;
  const int G = tid >> 8;              // split-K group (4 waves each)
  const int t = tid & 255;
  const int wave = t >> 6, lane = t & 63;
  const int lr = lane & 15, quad = lane >> 4;

  // uniform split of the pair's 65 kt-tiles:
  // tile A (p):  kts 0..p      (p+1), diag kt=p
  // tile B (pB): kts 0..pB     (64-p), diag kt=pB
  const int hA = (p + 2) >> 1;         // group0's A-count
  const int hB = (65 - p) >> 1;        // group0's B-count (hA+hB == 33)
  const int myA = G ? (p + 1 - hA) : hA;
  const int myB = G ? (64 - p - hB) : hB;
  const int aB = G ? hA : 0;           // my first A-kt
  const int bB = G ? hB : 0;           // my first B-kt
  const int mysteps = myA + myB;       // 33 (G0) or 32 (G1)

  bf16* const Kb0 = KV[G][0][0];
  bf16* const Kb1 = KV[G][1][0];
  bf16* const Vb0 = KV[G][0][1];
  bf16* const Vb1 = KV[G][1][1];

  // staging geometry (group-local): rows sr, sr+32, cols sc..sc+7
  const int sr = t >> 3;
  const int s8 = t & 7;
  const int sc = s8 * 8;
  const int vA = 32 * (s8 >> 2) + 16 * (s8 & 1) + 4 * ((s8 >> 1) & 1);
  const bf16* ksrc0 = Kh + (size_t)sr * 64 + sc;   // + kt*4096
  const bf16* ksrc1 = ksrc0 + 32 * 64;
  const bf16* vsrc0 = Vth + (size_t)sr * T + sc;   // + kt*64
  const bf16* vsrc1 = vsrc0 + (size_t)32 * T;
  const int d0 = lsw(sr, sc);
  const int d1 = lsw(sr + 32, sc);

  // kt index of step s (wave-uniform)
  const int kt0 = (0 < myA) ? aB : bB;

  // issue first K/V tile loads early (land during Q staging)
  short8 rk0 = *(const short8*)(ksrc0 + (size_t)kt0 * 4096);
  short8 rk1 = *(const short8*)(ksrc1 + (size_t)kt0 * 4096);
  short8 rv0 = *(const short8*)(vsrc0 + (size_t)kt0 * 64);
  short8 rv1 = *(const short8*)(vsrc1 + (size_t)kt0 * 64);

  // Q staging: tile A -> G0's Kb1 region, tile B -> G1's Kb1 region.
  // 512 threads x one short8 each per tile covers 64x64 exactly.
  {
    int rr = tid >> 3, c = (tid & 7) * 8;
    *(short8*)&KV[0][1][0][lsw(rr, c)] =
        *(const short8*)&Qh[(size_t)(p * 64 + rr) * 64 + c];
    *(short8*)&KV[1][1][0][lsw(rr, c)] =
        *(const short8*)&Qh[(size_t)(pB * 64 + rr) * 64 + c];
  }
  __syncthreads();
  short8 qfA0 = *(const short8*)&KV[0][1][0][lsw(wave * 16 + lr, quad * 8)];
  short8 qfA1 = *(const short8*)&KV[0][1][0][lsw(wave * 16 + lr, 32 + quad * 8)];
  short8 qfB0 = *(const short8*)&KV[1][1][0][lsw(wave * 16 + lr, quad * 8)];
  short8 qfB1 = *(const short8*)&KV[1][1][0][lsw(wave * 16 + lr, 32 + quad * 8)];
  // first K/V staging into my group's buf 0 (disjoint from both Kb1 regions)
  *(short8*)&Kb0[d0] = rk0;
  *(short8*)&Kb0[d1] = rk1;
  vstore_perm(Vb0, sr, vA, rv0);
  vstore_perm(Vb0, sr + 32, vA, rv1);
  __syncthreads();  // qf reads done + both groups' buf 0 staged

  short8 ones;
#pragma unroll
  for (int j = 0; j < 8; j++) ones[j] = (short)0x3F80;  // bf16 1.0

  float4v OA[4] = {}, OB[4] = {};
  float4v LA = {}, LB = {};

  for (int s = 0; s < 33; s++) {       // SMAX = 33 (G1 idles its last step)
    const bool act = s < mysteps;
    const bool pf = s + 1 < mysteps;
    if (pf) {  // issue next step's global loads before compute
      const int sn = s + 1;
      const int ktn = (sn < myA) ? (aB + sn) : (bB + (sn - myA));
      rk0 = *(const short8*)(ksrc0 + (size_t)ktn * 4096);
      rk1 = *(const short8*)(ksrc1 + (size_t)ktn * 4096);
      rv0 = *(const short8*)(vsrc0 + (size_t)ktn * 64);
      rv1 = *(const short8*)(vsrc1 + (size_t)ktn * 64);
    }

    if (act) {
      const bf16* Kc = (s & 1) ? Kb1 : Kb0;
      const bf16* Vc = (s & 1) ? Vb1 : Vb0;
      if (s < myA) {
        const int kt = aB + s;
        if (kt == p) attn_step<true>(Kc, Vc, qfA0, qfA1, ones, wave, lr, quad, LA, OA);
        else         attn_step<false>(Kc, Vc, qfA0, qfA1, ones, wave, lr, quad, LA, OA);
      } else {
        const int kt = bB + (s - myA);
        if (kt == pB) attn_step<true>(Kc, Vc, qfB0, qfB1, ones, wave, lr, quad, LB, OB);
        else          attn_step<false>(Kc, Vc, qfB0, qfB1, ones, wave, lr, quad, LB, OB);
      }
    }

    if (pf) {  // store prefetched tile to the other buffer
      bf16* Kn = (s & 1) ? Kb0 : Kb1;
      bf16* Vn = (s & 1) ? Vb0 : Vb1;
      *(short8*)&Kn[d0] = rk0;
      *(short8*)&Kn[d1] = rk1;
      vstore_perm(Vn, sr, vA, rv0);
      vstore_perm(Vn, sr + 32, vA, rv1);
    }
    __syncthreads();  // single barrier per step (both groups, same count)
  }

  // ---- split-k combine: G1 dumps partials (both tiles) into LDS ----------
  float* OpA = (float*)&KV[1][0][0][0];  // 16 KB (G1 dbuf0 K+V)
  float* OpB = (float*)&KV[1][1][0][0];  // 16 KB (G1 dbuf1 K+V)
  float* LpA = (float*)&KV[0][0][0][0];  // 64 f32 (G0 region, staging dead)
  float* LpB = LpA + 64;
  const int r0 = wave * 16 + quad * 4;
  if (G == 1) {
#pragma unroll
    for (int nc = 0; nc < 4; nc++)
#pragma unroll
      for (int i = 0; i < 4; i++) {
        OpA[(r0 + i) * 64 + nc * 16 + lr] = OA[nc][i];
        OpB[(r0 + i) * 64 + nc * 16 + lr] = OB[nc][i];
      }
    if (lr == 0) {
#pragma unroll
      for (int i = 0; i < 4; i++) { LpA[r0 + i] = LA[i]; LpB[r0 + i] = LB[i]; }
    }
  }
  __syncthreads();
  if (G == 0) {
    float invA[4], invB[4];
#pragma unroll
    for (int i = 0; i < 4; i++) {
      invA[i] = 1.f / (LA[i] + LpA[r0 + i]);
      invB[i] = 1.f / (LB[i] + LpB[r0 + i]);
    }
    const size_t ybA = ((size_t)b * T + p * 64 + r0) * 512 + h * 64;
    const size_t ybB = ((size_t)b * T + pB * 64 + r0) * 512 + h * 64;
#pragma unroll
    for (int nc = 0; nc < 4; nc++)
#pragma unroll
      for (int i = 0; i < 4; i++) {
        float oa = OA[nc][i] + OpA[(r0 + i) * 64 + nc * 16 + lr];
        float ob = OB[nc][i] + OpB[(r0 + i) * 64 + nc * 16 + lr];
        Y[ybA + (size_t)i * 512 + nc * 16 + lr] = (bf16)(oa * invA[i]);
        Y[ybB + (size_t)i * 512 + nc * 16 + lr] = (bf16)(ob * invB[i]);
      }
  }
}

// ---------------------------------------------------------------------------
extern "C" void kernel_launch(void* const* d_in, const int* in_sizes, int n_in,
                              void* d_out, int out_size, void* d_ws, size_t ws_size,
                              hipStream_t stream) {
  (void)out_size; (void)ws_size;
  // Interface verified R9: dict-order slots, fp32 in, x=[B,T,C], fp32 out.
  const int NX = 8192 * 512;
  int xi = 0;
  for (int i = 0; i < n_in; i++)
    if (in_sizes[i] == NX) { xi = i; break; }
  const float* x = (const float*)d_in[xi];
  const float* wsrc[4];
  int wn = 0;
  for (int i = 0; i < n_in && wn < 4; i++)
    if (i != xi) wsrc[wn++] = (const float*)d_in[i];

  bf16* ws = (bf16*)d_ws;
  const size_t HE = (size_t)NX;
  bf16* q  = ws;                 // 8 MB
  bf16* k  = q + HE;             // 8 MB
  bf16* yx = k + HE;             // 8 MB: bf16 x during qkv, y after attn
  bf16* cw = yx + HE;            // 2 MB (4 weights)  -> 26 MB ws total
  bf16* vt = (bf16*)d_out;       // V^T staged in d_out, consumed before proj
  float* out = (float*)d_out;

  conv_all<<<2560, 256, 0, stream>>>(x, wsrc[0], wsrc[1], wsrc[2], wsrc[3],
                                     yx, cw);
  qkv_kernel<<<dim3(64, 4, 3), 256, 0, stream>>>(yx, cw, q, k, vt);
  attn_kernel<<<512, 512, 0, stream>>>(q, k, vt, yx);
  proj_kernel<<<dim3(128, 4), 256, 0, stream>>>(yx, cw + 3 * 262144, out);
}